// Round 1
// baseline (554.214 us; speedup 1.0000x reference)
//
#include <hip/hip_runtime.h>

// ---------------------------------------------------------------------------
// Round 0: correct baseline for the DiT attention block on gfx950.
// Pipeline: cond MLP -> weight transpose/cast(bf16) -> LN+FiLM(bf16)
//           -> GEMM q -> GEMM kv -> flash attention -> GEMM out(fp32)
// ---------------------------------------------------------------------------

typedef __bf16 bf16x8 __attribute__((ext_vector_type(8)));
typedef float  f32x4  __attribute__((ext_vector_type(4)));
using u16 = unsigned short;
using u32 = unsigned int;

#define DIM   1024
#define NTOK  2048
#define NB    2
#define HEADS 16
#define DHEAD 64

__device__ __forceinline__ u16 f2bf(float f) {
  u32 u = __builtin_bit_cast(u32, f);
  u += 0x7fffu + ((u >> 16) & 1u);   // RNE
  return (u16)(u >> 16);
}

// ---------------------------------------------------------------------------
// 1) FiLM conditioning MLP: cond[b][j] = silu(ce[b]) . cond_W[:,j] + cond_b[j]
// ---------------------------------------------------------------------------
__global__ void cond_mlp(const float* __restrict__ ce, const float* __restrict__ W,
                         const float* __restrict__ bias, float* __restrict__ cond) {
  int id = blockIdx.x * 256 + threadIdx.x;   // 0..4095
  int b = id >> 11, j = id & 2047;
  const float* cb = ce + b * 1024;
  float acc = 0.f;
  for (int k = 0; k < 1024; ++k) {
    float t = cb[k];
    float s = t / (1.f + __expf(-t));        // silu
    acc += s * W[k * 2048 + j];
  }
  cond[id] = acc + bias[j];
}

// ---------------------------------------------------------------------------
// 2) transpose + cast: in fp32 [R][C] -> out bf16 [C][R]
// ---------------------------------------------------------------------------
__global__ void transpose_cast(const float* __restrict__ in, u16* __restrict__ out,
                               int R, int C) {
  __shared__ float tile[32][33];
  int tx = threadIdx.x & 31, ty = threadIdx.x >> 5;       // 32 x 8
  int c0 = blockIdx.x * 32, r0 = blockIdx.y * 32;
#pragma unroll
  for (int i = 0; i < 4; ++i) {
    int r = ty + i * 8;
    tile[r][tx] = in[(size_t)(r0 + r) * C + c0 + tx];
  }
  __syncthreads();
#pragma unroll
  for (int i = 0; i < 4; ++i) {
    int cc = ty + i * 8;
    out[(size_t)(c0 + cc) * R + r0 + tx] = f2bf(tile[tx][cc]);
  }
}

// ---------------------------------------------------------------------------
// 3) LayerNorm + FiLM modulate, fp32 -> bf16.  One row (1024) per block.
// ---------------------------------------------------------------------------
__global__ __launch_bounds__(256)
void ln_film(const float* __restrict__ x, const float* __restrict__ gamma,
             const float* __restrict__ cond, u16* __restrict__ xb) {
  int row = blockIdx.x;          // 0..4095
  int b = row >> 11;
  const float4 v = ((const float4*)(x + (size_t)row * DIM))[threadIdx.x];
  float s1 = v.x + v.y + v.z + v.w;
  float s2 = v.x * v.x + v.y * v.y + v.z * v.z + v.w * v.w;
#pragma unroll
  for (int m = 1; m <= 32; m <<= 1) {
    s1 += __shfl_xor(s1, m);
    s2 += __shfl_xor(s2, m);
  }
  __shared__ float red[8];
  int w = threadIdx.x >> 6, l = threadIdx.x & 63;
  if (l == 0) { red[w * 2] = s1; red[w * 2 + 1] = s2; }
  __syncthreads();
  s1 = red[0] + red[2] + red[4] + red[6];
  s2 = red[1] + red[3] + red[5] + red[7];
  float mu = s1 * (1.f / DIM);
  float var = s2 * (1.f / DIM) - mu * mu;
  float rstd = rsqrtf(var + 1e-5f);

  const float4 g  = ((const float4*)gamma)[threadIdx.x];
  const float4 sc = ((const float4*)(cond + b * 2048))[threadIdx.x];
  const float4 sh = ((const float4*)(cond + b * 2048 + 1024))[threadIdx.x];
  float y0 = (v.x - mu) * rstd * g.x * (sc.x + 1.f) + sh.x;
  float y1 = (v.y - mu) * rstd * g.y * (sc.y + 1.f) + sh.y;
  float y2 = (v.z - mu) * rstd * g.z * (sc.z + 1.f) + sh.z;
  float y3 = (v.w - mu) * rstd * g.w * (sc.w + 1.f) + sh.w;
  u32 p0 = (u32)f2bf(y0) | ((u32)f2bf(y1) << 16);
  u32 p1 = (u32)f2bf(y2) | ((u32)f2bf(y3) << 16);
  ((uint2*)(xb + (size_t)row * DIM))[threadIdx.x] = make_uint2(p0, p1);
}

// ---------------------------------------------------------------------------
// 4) bf16 MFMA GEMM, m97 structure: C[M,N] = A[M,K] * Bt[N,K]^T
//    128x128 tile, BK=32, 4 waves (each 64x64 = 4x4 16x16 fragments),
//    global_load_lds(16B) staging, linear LDS.
//    MODE 0: Q epilogue (scale 0.125, scatter [b,h,tok,d])
//    MODE 1: KV epilogue (K -> [b,h,tok,d], V -> [b,h,d,tok])
//    MODE 2: fp32 row-major output (stride 1024)
// ---------------------------------------------------------------------------
#define BM 128
#define BN 128
#define BK 32

template <int MODE>
__global__ __launch_bounds__(256, 2)
void gemm_bt(const u16* __restrict__ A, const u16* __restrict__ Bt,
             void* __restrict__ out1, void* __restrict__ out2, int K) {
  __shared__ __align__(16) u16 aT[BM * BK];
  __shared__ __align__(16) u16 bT[BN * BK];
  const int t = threadIdx.x;
  const int w = t >> 6, l = t & 63, lr = l & 15, lg = l >> 4;
  const int wr = w >> 1, wc = w & 1;
  const int m0 = blockIdx.y * BM, n0 = blockIdx.x * BN;

  f32x4 acc[4][4] = {};

  const int nkt = K / BK;
  for (int kt = 0; kt < nkt; ++kt) {
    const u16* Asrc = A + (size_t)m0 * K + kt * BK;
    const u16* Bsrc = Bt + (size_t)n0 * K + kt * BK;
#pragma unroll
    for (int i = 0; i < 2; ++i) {
      int c = i * 256 + w * 64 + l;          // 16B chunk id, 0..511
      int row = c >> 2, cb = (c & 3) * 8;
      __builtin_amdgcn_global_load_lds(
          (const __attribute__((address_space(1))) void*)(Asrc + (size_t)row * K + cb),
          (__attribute__((address_space(3))) void*)(aT + (size_t)(i * 256 + w * 64) * 8),
          16, 0, 0);
    }
#pragma unroll
    for (int i = 0; i < 2; ++i) {
      int c = i * 256 + w * 64 + l;
      int row = c >> 2, cb = (c & 3) * 8;
      __builtin_amdgcn_global_load_lds(
          (const __attribute__((address_space(1))) void*)(Bsrc + (size_t)row * K + cb),
          (__attribute__((address_space(3))) void*)(bT + (size_t)(i * 256 + w * 64) * 8),
          16, 0, 0);
    }
    __syncthreads();

    bf16x8 af[4], bfr[4];
#pragma unroll
    for (int mt = 0; mt < 4; ++mt)
      af[mt] = *(const bf16x8*)(aT + (wr * 64 + mt * 16 + lr) * BK + lg * 8);
#pragma unroll
    for (int nt = 0; nt < 4; ++nt)
      bfr[nt] = *(const bf16x8*)(bT + (wc * 64 + nt * 16 + lr) * BK + lg * 8);
#pragma unroll
    for (int mt = 0; mt < 4; ++mt)
#pragma unroll
      for (int nt = 0; nt < 4; ++nt)
        acc[mt][nt] = __builtin_amdgcn_mfma_f32_16x16x32_bf16(af[mt], bfr[nt],
                                                              acc[mt][nt], 0, 0, 0);
    __syncthreads();
  }

  // epilogue: C/D layout col = lane&15, row = (lane>>4)*4 + reg
#pragma unroll
  for (int mt = 0; mt < 4; ++mt) {
#pragma unroll
    for (int nt = 0; nt < 4; ++nt) {
#pragma unroll
      for (int r = 0; r < 4; ++r) {
        int gm = m0 + wr * 64 + mt * 16 + lg * 4 + r;  // token row (b*2048+tok)
        int gn = n0 + wc * 64 + nt * 16 + lr;          // output column
        float v = acc[mt][nt][r];
        if (MODE == 0) {
          int b = gm >> 11, tok = gm & 2047;
          int h = gn >> 6, d = gn & 63;
          ((u16*)out1)[(((size_t)(b * HEADS + h) * NTOK + tok) << 6) + d] =
              f2bf(v * 0.125f);
        } else if (MODE == 1) {
          int b = gm >> 11, tok = gm & 2047;
          if (gn < 1024) {   // K part (block-uniform branch)
            int h = gn >> 6, d = gn & 63;
            ((u16*)out1)[(((size_t)(b * HEADS + h) * NTOK + tok) << 6) + d] = f2bf(v);
          } else {           // V part, stored transposed [b,h,d,tok]
            int c2 = gn - 1024;
            int h = c2 >> 6, d = c2 & 63;
            ((u16*)out2)[((size_t)(b * HEADS + h) * DHEAD + d) * NTOK + tok] = f2bf(v);
          }
        } else {
          ((float*)out1)[(size_t)gm * DIM + gn] = v;
        }
      }
    }
  }
}

// ---------------------------------------------------------------------------
// 5) Flash attention. Grid (N/64, B*H). 4 waves/block, wave owns 16 q-rows.
//    KV tile = 64. Q/K/Vt fragments read directly from global (L2-resident).
// ---------------------------------------------------------------------------
__global__ __launch_bounds__(256, 2)
void attn_kernel(const u16* __restrict__ Q, const u16* __restrict__ K,
                 const u16* __restrict__ Vt, u16* __restrict__ Aout) {
  __shared__ __align__(16) u16 plds[4][16][72];   // +8 pad: b128 reads spread 8 lanes/span
  int bh = blockIdx.y;
  int b = bh >> 4, h = bh & 15;
  int w = threadIdx.x >> 6, l = threadIdx.x & 63, lr = l & 15, lg = l >> 4;
  int q0 = blockIdx.x * 64 + w * 16;
  const u16* Qh = Q + ((size_t)bh << 17);   // 2048*64
  const u16* Kh = K + ((size_t)bh << 17);
  const u16* Vh = Vt + ((size_t)bh << 17);

  bf16x8 qf[2];
  qf[0] = *(const bf16x8*)(Qh + (size_t)(q0 + lr) * 64 + lg * 8);
  qf[1] = *(const bf16x8*)(Qh + (size_t)(q0 + lr) * 64 + 32 + lg * 8);

  f32x4 o[4] = {};
  float mm[4] = {-1e30f, -1e30f, -1e30f, -1e30f};
  float ls[4] = {0.f, 0.f, 0.f, 0.f};

  for (int kv0 = 0; kv0 < NTOK; kv0 += 64) {
    f32x4 s[4] = {};
#pragma unroll
    for (int kt = 0; kt < 2; ++kt) {
#pragma unroll
      for (int nt = 0; nt < 4; ++nt) {
        bf16x8 kf = *(const bf16x8*)(Kh + (size_t)(kv0 + nt * 16 + lr) * 64 + kt * 32 + lg * 8);
        s[nt] = __builtin_amdgcn_mfma_f32_16x16x32_bf16(qf[kt], kf, s[nt], 0, 0, 0);
      }
    }
    // online softmax; row (4*lg + r) lives in the 16 lanes of group lg at reg r
    float al[4];
#pragma unroll
    for (int r = 0; r < 4; ++r) {
      float tm = fmaxf(fmaxf(s[0][r], s[1][r]), fmaxf(s[2][r], s[3][r]));
      tm = fmaxf(tm, __shfl_xor(tm, 1));
      tm = fmaxf(tm, __shfl_xor(tm, 2));
      tm = fmaxf(tm, __shfl_xor(tm, 4));
      tm = fmaxf(tm, __shfl_xor(tm, 8));
      float mn = fmaxf(mm[r], tm);
      al[r] = __expf(mm[r] - mn);
      mm[r] = mn;
      float rs = 0.f;
#pragma unroll
      for (int nt = 0; nt < 4; ++nt) {
        float p = __expf(s[nt][r] - mn);
        s[nt][r] = p;
        rs += p;
      }
      rs += __shfl_xor(rs, 1);
      rs += __shfl_xor(rs, 2);
      rs += __shfl_xor(rs, 4);
      rs += __shfl_xor(rs, 8);
      ls[r] = ls[r] * al[r] + rs;
    }
    // P -> LDS (re-layout D-frag -> A-frag), per-wave buffer, no barrier needed
#pragma unroll
    for (int nt = 0; nt < 4; ++nt)
#pragma unroll
      for (int r = 0; r < 4; ++r)
        plds[w][lg * 4 + r][nt * 16 + lr] = f2bf(s[nt][r]);
    // rescale O before accumulating this tile
#pragma unroll
    for (int nt = 0; nt < 4; ++nt)
#pragma unroll
      for (int r = 0; r < 4; ++r) o[nt][r] *= al[r];
    // PV: O[q][d] += P[q][kv] * V[kv][d], V read from Vt[d][kv] (contiguous)
#pragma unroll
    for (int kt = 0; kt < 2; ++kt) {
      bf16x8 pf = *(const bf16x8*)(&plds[w][lr][kt * 32 + lg * 8]);
#pragma unroll
      for (int nt = 0; nt < 4; ++nt) {
        bf16x8 vf = *(const bf16x8*)(Vh + (size_t)(nt * 16 + lr) * NTOK + kv0 + kt * 32 + lg * 8);
        o[nt] = __builtin_amdgcn_mfma_f32_16x16x32_bf16(pf, vf, o[nt], 0, 0, 0);
      }
    }
  }
  // write attn output [tok_global][h*64+d] bf16
#pragma unroll
  for (int r = 0; r < 4; ++r) {
    float inv = 1.f / ls[r];
    int tok = q0 + lg * 4 + r;
#pragma unroll
    for (int nt = 0; nt < 4; ++nt) {
      int d = nt * 16 + lr;
      Aout[((size_t)(b * NTOK + tok)) * DIM + h * DHEAD + d] = f2bf(o[nt][r] * inv);
    }
  }
}

// ---------------------------------------------------------------------------
// launch
// ---------------------------------------------------------------------------
extern "C" void kernel_launch(void* const* d_in, const int* in_sizes, int n_in,
                              void* d_out, int out_size, void* d_ws, size_t ws_size,
                              hipStream_t stream) {
  const float* x     = (const float*)d_in[0];
  const float* ce    = (const float*)d_in[1];
  const float* gamma = (const float*)d_in[2];
  const float* cW    = (const float*)d_in[3];
  const float* cb    = (const float*)d_in[4];
  const float* Wq    = (const float*)d_in[5];
  const float* Wkv   = (const float*)d_in[6];
  const float* Wo    = (const float*)d_in[7];
  float* out = (float*)d_out;

  char* ws = (char*)d_ws;
  float* cond = (float*)ws;                               // 16 KB
  u16* WqT  = (u16*)(ws + (16 << 10));                    // 2 MB
  u16* WkvT = (u16*)(ws + (16 << 10) + (2u << 20));       // 4 MB
  u16* WoT  = (u16*)(ws + (16 << 10) + (6u << 20));       // 2 MB
  u16* xb   = (u16*)(ws + (16 << 10) + (8u << 20));       // 8 MB
  u16* Qb   = (u16*)(ws + (16 << 10) + (16u << 20));      // 8 MB
  u16* Kb   = (u16*)(ws + (16 << 10) + (24u << 20));      // 8 MB
  u16* Vtb  = (u16*)(ws + (16 << 10) + (32u << 20));      // 8 MB
  u16* Ab   = (u16*)(ws + (16 << 10) + (40u << 20));      // 8 MB

  cond_mlp<<<16, 256, 0, stream>>>(ce, cW, cb, cond);
  transpose_cast<<<dim3(32, 32), 256, 0, stream>>>(Wq, WqT, 1024, 1024);
  transpose_cast<<<dim3(64, 32), 256, 0, stream>>>(Wkv, WkvT, 1024, 2048);
  transpose_cast<<<dim3(32, 32), 256, 0, stream>>>(Wo, WoT, 1024, 1024);
  ln_film<<<4096, 256, 0, stream>>>(x, gamma, cond, xb);
  gemm_bt<0><<<dim3(8, 32), 256, 0, stream>>>(xb, WqT, Qb, nullptr, 1024);
  gemm_bt<1><<<dim3(16, 32), 256, 0, stream>>>(xb, WkvT, Kb, Vtb, 1024);
  attn_kernel<<<dim3(32, 32), 256, 0, stream>>>(Qb, Kb, Vtb, Ab);
  gemm_bt<2><<<dim3(8, 32), 256, 0, stream>>>(Ab, WoT, out, nullptr, 1024);
}

// Round 2
// 307.981 us; speedup vs baseline: 1.7995x; 1.7995x over previous
//
#include <hip/hip_runtime.h>

// ---------------------------------------------------------------------------
// Round 1: attn rewritten as 2-phase double-buffered LDS pipeline with
// XOR-swizzled K/Vt tiles (shared across waves); Vt produced by a
// swapped-operand GEMM (coalesced stores); Q+K projections fused.
// ---------------------------------------------------------------------------

typedef __bf16 bf16x8 __attribute__((ext_vector_type(8)));
typedef float  f32x4  __attribute__((ext_vector_type(4)));
using u16 = unsigned short;
using u32 = unsigned int;

#define DIM   1024
#define NTOK  2048
#define HEADS 16
#define DHEAD 64

__device__ __forceinline__ u16 f2bf(float f) {
  u32 u = __builtin_bit_cast(u32, f);
  u += 0x7fffu + ((u >> 16) & 1u);   // RNE
  return (u16)(u >> 16);
}

// ---------------------------------------------------------------------------
// 1) FiLM conditioning MLP, split-K with atomics. grid 128 = b(2) x kb(8) x jb(8)
// ---------------------------------------------------------------------------
__global__ void cond_mlp(const float* __restrict__ ce, const float* __restrict__ W,
                         const float* __restrict__ bias, float* __restrict__ cond) {
  int b  = blockIdx.x >> 6;
  int kb = (blockIdx.x >> 3) & 7;
  int j  = (blockIdx.x & 7) * 256 + threadIdx.x;     // 0..2047
  const float* cb = ce + b * 1024;
  float acc = (kb == 0) ? bias[j] : 0.f;
  int k0 = kb * 128;
  for (int k = k0; k < k0 + 128; ++k) {
    float t = cb[k];
    float s = t / (1.f + __expf(-t));                // silu
    acc += s * W[k * 2048 + j];
  }
  atomicAdd(&cond[b * 2048 + j], acc);
}

// ---------------------------------------------------------------------------
// 2) transpose + cast: in fp32 [R][C] -> out bf16 [C][R]
// ---------------------------------------------------------------------------
__global__ void transpose_cast(const float* __restrict__ in, u16* __restrict__ out,
                               int R, int C) {
  __shared__ float tile[32][33];
  int tx = threadIdx.x & 31, ty = threadIdx.x >> 5;       // 32 x 8
  int c0 = blockIdx.x * 32, r0 = blockIdx.y * 32;
#pragma unroll
  for (int i = 0; i < 4; ++i) {
    int r = ty + i * 8;
    tile[r][tx] = in[(size_t)(r0 + r) * C + c0 + tx];
  }
  __syncthreads();
#pragma unroll
  for (int i = 0; i < 4; ++i) {
    int cc = ty + i * 8;
    out[(size_t)(c0 + cc) * R + r0 + tx] = f2bf(tile[tx][cc]);
  }
}

// ---------------------------------------------------------------------------
// 3) LayerNorm + FiLM modulate, fp32 -> bf16.  One row (1024) per block.
// ---------------------------------------------------------------------------
__global__ __launch_bounds__(256)
void ln_film(const float* __restrict__ x, const float* __restrict__ gamma,
             const float* __restrict__ cond, u16* __restrict__ xb) {
  int row = blockIdx.x;          // 0..4095
  int b = row >> 11;
  const float4 v = ((const float4*)(x + (size_t)row * DIM))[threadIdx.x];
  float s1 = v.x + v.y + v.z + v.w;
  float s2 = v.x * v.x + v.y * v.y + v.z * v.z + v.w * v.w;
#pragma unroll
  for (int m = 1; m <= 32; m <<= 1) {
    s1 += __shfl_xor(s1, m);
    s2 += __shfl_xor(s2, m);
  }
  __shared__ float red[8];
  int w = threadIdx.x >> 6, l = threadIdx.x & 63;
  if (l == 0) { red[w * 2] = s1; red[w * 2 + 1] = s2; }
  __syncthreads();
  s1 = red[0] + red[2] + red[4] + red[6];
  s2 = red[1] + red[3] + red[5] + red[7];
  float mu = s1 * (1.f / DIM);
  float var = s2 * (1.f / DIM) - mu * mu;
  float rstd = rsqrtf(var + 1e-5f);

  const float4 g  = ((const float4*)gamma)[threadIdx.x];
  const float4 sc = ((const float4*)(cond + b * 2048))[threadIdx.x];
  const float4 sh = ((const float4*)(cond + b * 2048 + 1024))[threadIdx.x];
  float y0 = (v.x - mu) * rstd * g.x * (sc.x + 1.f) + sh.x;
  float y1 = (v.y - mu) * rstd * g.y * (sc.y + 1.f) + sh.y;
  float y2 = (v.z - mu) * rstd * g.z * (sc.z + 1.f) + sh.z;
  float y3 = (v.w - mu) * rstd * g.w * (sc.w + 1.f) + sh.w;
  u32 p0 = (u32)f2bf(y0) | ((u32)f2bf(y1) << 16);
  u32 p1 = (u32)f2bf(y2) | ((u32)f2bf(y3) << 16);
  ((uint2*)(xb + (size_t)row * DIM))[threadIdx.x] = make_uint2(p0, p1);
}

// ---------------------------------------------------------------------------
// 4) bf16 MFMA GEMM, m97 structure: C[M,N] = A[M,K] * Bt[N,K]^T, K=1024
//    MODE 0: fused QK epilogue (gn<1024 -> Q *0.125, else K), scatter [b,h,tok,d]
//    MODE 2: fp32 row-major output (stride 1024)
//    MODE 3: Vt  (A=WvT, Bt=xb): out[(b*1024+gm)*2048 + tok], coalesced
// ---------------------------------------------------------------------------
#define BM 128
#define BN 128
#define BK 32

template <int MODE>
__global__ __launch_bounds__(256, 2)
void gemm_bt(const u16* __restrict__ A, const u16* __restrict__ Bt,
             void* __restrict__ out1, void* __restrict__ out2, int K) {
  __shared__ __align__(16) u16 aT[BM * BK];
  __shared__ __align__(16) u16 bT[BN * BK];
  const int t = threadIdx.x;
  const int w = t >> 6, l = t & 63, lr = l & 15, lg = l >> 4;
  const int wr = w >> 1, wc = w & 1;
  const int m0 = blockIdx.y * BM, n0 = blockIdx.x * BN;

  f32x4 acc[4][4] = {};

  const int nkt = K / BK;
  for (int kt = 0; kt < nkt; ++kt) {
    const u16* Asrc = A + (size_t)m0 * K + kt * BK;
    const u16* Bsrc = Bt + (size_t)n0 * K + kt * BK;
#pragma unroll
    for (int i = 0; i < 2; ++i) {
      int c = i * 256 + w * 64 + l;          // 16B chunk id, 0..511
      int row = c >> 2, cb = (c & 3) * 8;
      __builtin_amdgcn_global_load_lds(
          (const __attribute__((address_space(1))) void*)(Asrc + (size_t)row * K + cb),
          (__attribute__((address_space(3))) void*)(aT + (size_t)(i * 256 + w * 64) * 8),
          16, 0, 0);
    }
#pragma unroll
    for (int i = 0; i < 2; ++i) {
      int c = i * 256 + w * 64 + l;
      int row = c >> 2, cb = (c & 3) * 8;
      __builtin_amdgcn_global_load_lds(
          (const __attribute__((address_space(1))) void*)(Bsrc + (size_t)row * K + cb),
          (__attribute__((address_space(3))) void*)(bT + (size_t)(i * 256 + w * 64) * 8),
          16, 0, 0);
    }
    __syncthreads();

    bf16x8 af[4], bfr[4];
#pragma unroll
    for (int mt = 0; mt < 4; ++mt)
      af[mt] = *(const bf16x8*)(aT + (wr * 64 + mt * 16 + lr) * BK + lg * 8);
#pragma unroll
    for (int nt = 0; nt < 4; ++nt)
      bfr[nt] = *(const bf16x8*)(bT + (wc * 64 + nt * 16 + lr) * BK + lg * 8);
    __builtin_amdgcn_s_setprio(1);
#pragma unroll
    for (int mt = 0; mt < 4; ++mt)
#pragma unroll
      for (int nt = 0; nt < 4; ++nt)
        acc[mt][nt] = __builtin_amdgcn_mfma_f32_16x16x32_bf16(af[mt], bfr[nt],
                                                              acc[mt][nt], 0, 0, 0);
    __builtin_amdgcn_s_setprio(0);
    __syncthreads();
  }

  // epilogue: C/D layout col = lane&15, row = (lane>>4)*4 + reg
#pragma unroll
  for (int mt = 0; mt < 4; ++mt) {
#pragma unroll
    for (int nt = 0; nt < 4; ++nt) {
#pragma unroll
      for (int r = 0; r < 4; ++r) {
        int gm = m0 + wr * 64 + mt * 16 + lg * 4 + r;
        int gn = n0 + wc * 64 + nt * 16 + lr;
        float v = acc[mt][nt][r];
        if (MODE == 0) {
          int b = gm >> 11, tok = gm & 2047;
          if (gn < 1024) {        // Q (block-uniform branch)
            int h = gn >> 6, d = gn & 63;
            ((u16*)out1)[(((size_t)(b * HEADS + h) * NTOK + tok) << 6) + d] =
                f2bf(v * 0.125f);
          } else {                // K
            int c2 = gn - 1024;
            int h = c2 >> 6, d = c2 & 63;
            ((u16*)out2)[(((size_t)(b * HEADS + h) * NTOK + tok) << 6) + d] = f2bf(v);
          }
        } else if (MODE == 3) {   // Vt: gm = h*64+d (0..1023), gn = b*2048+tok
          ((u16*)out1)[(((size_t)(gn >> 11) * 1024 + gm) << 11) + (gn & 2047)] = f2bf(v);
        } else {
          ((float*)out1)[(size_t)gm * DIM + gn] = v;
        }
      }
    }
  }
}

// ---------------------------------------------------------------------------
// 5) Flash attention, 2-phase double-buffered LDS pipeline.
//    Grid (N/64, B*H), 4 waves/block (wave = 16 q-rows), KV tile = 64.
//    K and Vt tiles staged via global_load_lds with XOR swizzle
//    (slot ^= row&7 applied on the global SOURCE, linear LDS dest,
//     same XOR on the ds_read side — rule #21).
// ---------------------------------------------------------------------------
__global__ __launch_bounds__(256, 3)
void attn_kernel(const u16* __restrict__ Q, const u16* __restrict__ K,
                 const u16* __restrict__ Vt, u16* __restrict__ Aout) {
  __shared__ __align__(16) u16 kbuf[2][64 * 64];
  __shared__ __align__(16) u16 vbuf[2][64 * 64];
  __shared__ __align__(16) u16 plds[4][16][88];   // 176B rows: b128-aligned, 2-way max
  int bh = blockIdx.y;
  int b = bh >> 4, h = bh & 15;
  int w = threadIdx.x >> 6, l = threadIdx.x & 63, lr = l & 15, lg = l >> 4;
  int q0 = blockIdx.x * 64 + w * 16;
  const u16* Qh = Q + ((size_t)bh << 17);   // 2048*64
  const u16* Kh = K + ((size_t)bh << 17);
  const u16* Vh = Vt + ((size_t)bh << 17);

  bf16x8 qf[2];
  qf[0] = *(const bf16x8*)(Qh + (size_t)(q0 + lr) * 64 + lg * 8);
  qf[1] = *(const bf16x8*)(Qh + (size_t)(q0 + lr) * 64 + 32 + lg * 8);

  f32x4 o[4] = {};
  float mm[4] = {-1e30f, -1e30f, -1e30f, -1e30f};
  float ls[4] = {0.f, 0.f, 0.f, 0.f};

  auto stage = [&](int buf, int kv0) {
#pragma unroll
    for (int i = 0; i < 2; ++i) {
      int c = i * 256 + threadIdx.x;                 // chunk 0..511
      int row = c >> 3;
      int ls_ = (c & 7) ^ (row & 7);                 // pre-swizzled source slot
      __builtin_amdgcn_global_load_lds(
          (const __attribute__((address_space(1))) void*)(Kh + (size_t)(kv0 + row) * 64 + ls_ * 8),
          (__attribute__((address_space(3))) void*)(&kbuf[buf][(i * 256 + w * 64) * 8]),
          16, 0, 0);
    }
#pragma unroll
    for (int i = 0; i < 2; ++i) {
      int c = i * 256 + threadIdx.x;
      int row = c >> 3;                              // row = d
      int ls_ = (c & 7) ^ (row & 7);
      __builtin_amdgcn_global_load_lds(
          (const __attribute__((address_space(1))) void*)(Vh + (size_t)row * NTOK + kv0 + ls_ * 8),
          (__attribute__((address_space(3))) void*)(&vbuf[buf][(i * 256 + w * 64) * 8]),
          16, 0, 0);
    }
  };

  stage(0, 0);
  __syncthreads();

  for (int t = 0; t < NTOK / 64; ++t) {
    int cur = t & 1;
    if (t < NTOK / 64 - 1) stage(cur ^ 1, (t + 1) * 64);

    const u16* kb = kbuf[cur];
    const u16* vb = vbuf[cur];

    f32x4 s[4] = {};
#pragma unroll
    for (int kt = 0; kt < 2; ++kt) {
      bf16x8 kf[4];
#pragma unroll
      for (int nt = 0; nt < 4; ++nt) {
        int row = nt * 16 + lr;
        int slot = (kt * 4 + lg) ^ (row & 7);
        kf[nt] = *(const bf16x8*)(kb + row * 64 + slot * 8);
      }
      __builtin_amdgcn_s_setprio(1);
#pragma unroll
      for (int nt = 0; nt < 4; ++nt)
        s[nt] = __builtin_amdgcn_mfma_f32_16x16x32_bf16(qf[kt], kf[nt], s[nt], 0, 0, 0);
      __builtin_amdgcn_s_setprio(0);
    }

    // online softmax; score[q=lg*4+r][kv=nt*16+lr]
    float al[4];
#pragma unroll
    for (int r = 0; r < 4; ++r) {
      float tm = fmaxf(fmaxf(s[0][r], s[1][r]), fmaxf(s[2][r], s[3][r]));
      tm = fmaxf(tm, __shfl_xor(tm, 1));
      tm = fmaxf(tm, __shfl_xor(tm, 2));
      tm = fmaxf(tm, __shfl_xor(tm, 4));
      tm = fmaxf(tm, __shfl_xor(tm, 8));
      float mn = fmaxf(mm[r], tm);
      al[r] = __expf(mm[r] - mn);
      mm[r] = mn;
      float rs = 0.f;
#pragma unroll
      for (int nt = 0; nt < 4; ++nt) {
        float p = __expf(s[nt][r] - mn);
        s[nt][r] = p;
        rs += p;
      }
      rs += __shfl_xor(rs, 1);
      rs += __shfl_xor(rs, 2);
      rs += __shfl_xor(rs, 4);
      rs += __shfl_xor(rs, 8);
      ls[r] = ls[r] * al[r] + rs;
    }
    // P -> per-wave LDS (re-layout D-frag -> A-frag); same-wave, no barrier
#pragma unroll
    for (int nt = 0; nt < 4; ++nt)
#pragma unroll
      for (int r = 0; r < 4; ++r)
        plds[w][lg * 4 + r][nt * 16 + lr] = f2bf(s[nt][r]);
    // rescale O
#pragma unroll
    for (int nt = 0; nt < 4; ++nt)
#pragma unroll
      for (int r = 0; r < 4; ++r) o[nt][r] *= al[r];
    // PV: O[q][d] += P[q][kv] * Vt[d][kv]^T
#pragma unroll
    for (int kt = 0; kt < 2; ++kt) {
      bf16x8 pf = *(const bf16x8*)(&plds[w][lr][kt * 32 + lg * 8]);
      bf16x8 vf[4];
#pragma unroll
      for (int nt = 0; nt < 4; ++nt) {
        int row = nt * 16 + lr;
        int slot = (kt * 4 + lg) ^ (row & 7);
        vf[nt] = *(const bf16x8*)(vb + row * 64 + slot * 8);
      }
      __builtin_amdgcn_s_setprio(1);
#pragma unroll
      for (int nt = 0; nt < 4; ++nt)
        o[nt] = __builtin_amdgcn_mfma_f32_16x16x32_bf16(pf, vf[nt], o[nt], 0, 0, 0);
      __builtin_amdgcn_s_setprio(0);
    }
    __syncthreads();   // drains prefetch (vmcnt) + flips buffer
  }

  // write attn output [tok][h*64+d] bf16
#pragma unroll
  for (int r = 0; r < 4; ++r) {
    float inv = 1.f / ls[r];
    int tok = q0 + lg * 4 + r;
#pragma unroll
    for (int nt = 0; nt < 4; ++nt) {
      int d = nt * 16 + lr;
      Aout[((size_t)(b * NTOK + tok)) * DIM + h * DHEAD + d] = f2bf(o[nt][r] * inv);
    }
  }
}

// ---------------------------------------------------------------------------
// launch
// ---------------------------------------------------------------------------
extern "C" void kernel_launch(void* const* d_in, const int* in_sizes, int n_in,
                              void* d_out, int out_size, void* d_ws, size_t ws_size,
                              hipStream_t stream) {
  const float* x     = (const float*)d_in[0];
  const float* ce    = (const float*)d_in[1];
  const float* gamma = (const float*)d_in[2];
  const float* cW    = (const float*)d_in[3];
  const float* cb    = (const float*)d_in[4];
  const float* Wq    = (const float*)d_in[5];
  const float* Wkv   = (const float*)d_in[6];
  const float* Wo    = (const float*)d_in[7];
  float* out = (float*)d_out;

  char* ws = (char*)d_ws;
  float* cond = (float*)ws;                               // 16 KB
  u16* WT   = (u16*)(ws + (16 << 10));                    // [3072][1024] bf16 = 6 MB
  u16* WoT  = (u16*)(ws + (16 << 10) + (6u << 20));       // 2 MB
  u16* xb   = (u16*)(ws + (16 << 10) + (8u << 20));       // 8 MB
  u16* Qb   = (u16*)(ws + (16 << 10) + (16u << 20));      // 8 MB
  u16* Kb   = (u16*)(ws + (16 << 10) + (24u << 20));      // 8 MB
  u16* Vtb  = (u16*)(ws + (16 << 10) + (32u << 20));      // 8 MB
  u16* Ab   = (u16*)(ws + (16 << 10) + (40u << 20));      // 8 MB
  u16* WvT  = WT + 2048 * 1024;

  hipMemsetAsync(cond, 0, 16 << 10, stream);
  cond_mlp<<<128, 256, 0, stream>>>(ce, cW, cb, cond);
  transpose_cast<<<dim3(32, 32), 256, 0, stream>>>(Wq, WT, 1024, 1024);           // rows 0..1023: Wq^T
  transpose_cast<<<dim3(64, 32), 256, 0, stream>>>(Wkv, WT + 1024 * 1024, 1024, 2048); // rows 1024..3071: Wk^T,Wv^T
  transpose_cast<<<dim3(32, 32), 256, 0, stream>>>(Wo, WoT, 1024, 1024);
  ln_film<<<4096, 256, 0, stream>>>(x, gamma, cond, xb);
  gemm_bt<0><<<dim3(16, 32), 256, 0, stream>>>(xb, WT, Qb, Kb, 1024);     // fused Q+K
  gemm_bt<3><<<dim3(32, 8), 256, 0, stream>>>(WvT, xb, Vtb, nullptr, 1024); // Vt = (x@Wv)^T
  attn_kernel<<<dim3(32, 32), 256, 0, stream>>>(Qb, Kb, Vtb, Ab);
  gemm_bt<2><<<dim3(8, 32), 256, 0, stream>>>(Ab, WoT, out, nullptr, 1024);
}

// Round 3
// 248.196 us; speedup vs baseline: 2.2330x; 1.2409x over previous
//
#include <hip/hip_runtime.h>

// ---------------------------------------------------------------------------
// Round 2: attn softmax made lane-local via swapped-operand MFMA (S^T = K·Q),
// P kept fully in registers (cvt_pk + permlane16/32_swap redistribution),
// 8 waves / 128 q-rows per block. Q pre-scaled by 0.125*log2e -> exp2.
// ---------------------------------------------------------------------------

typedef __bf16 bf16x8 __attribute__((ext_vector_type(8)));
typedef float  f32x4  __attribute__((ext_vector_type(4)));
typedef unsigned int u32x4 __attribute__((ext_vector_type(4)));
using u16 = unsigned short;
using u32 = unsigned int;

#define DIM   1024
#define NTOK  2048
#define HEADS 16
#define DHEAD 64

__device__ __forceinline__ u16 f2bf(float f) {
  u32 u = __builtin_bit_cast(u32, f);
  u += 0x7fffu + ((u >> 16) & 1u);   // RNE
  return (u16)(u >> 16);
}

// ---------------------------------------------------------------------------
// 1) FiLM conditioning MLP, split-K with atomics. grid 128 = b(2) x kb(8) x jb(8)
// ---------------------------------------------------------------------------
__global__ void cond_mlp(const float* __restrict__ ce, const float* __restrict__ W,
                         const float* __restrict__ bias, float* __restrict__ cond) {
  int b  = blockIdx.x >> 6;
  int kb = (blockIdx.x >> 3) & 7;
  int j  = (blockIdx.x & 7) * 256 + threadIdx.x;     // 0..2047
  const float* cb = ce + b * 1024;
  float acc = (kb == 0) ? bias[j] : 0.f;
  int k0 = kb * 128;
  for (int k = k0; k < k0 + 128; ++k) {
    float t = cb[k];
    float s = t / (1.f + __expf(-t));                // silu
    acc += s * W[k * 2048 + j];
  }
  atomicAdd(&cond[b * 2048 + j], acc);
}

// ---------------------------------------------------------------------------
// 2) transpose + cast: in fp32 [R][C] -> out bf16 [C][R]
// ---------------------------------------------------------------------------
__global__ void transpose_cast(const float* __restrict__ in, u16* __restrict__ out,
                               int R, int C) {
  __shared__ float tile[32][33];
  int tx = threadIdx.x & 31, ty = threadIdx.x >> 5;       // 32 x 8
  int c0 = blockIdx.x * 32, r0 = blockIdx.y * 32;
#pragma unroll
  for (int i = 0; i < 4; ++i) {
    int r = ty + i * 8;
    tile[r][tx] = in[(size_t)(r0 + r) * C + c0 + tx];
  }
  __syncthreads();
#pragma unroll
  for (int i = 0; i < 4; ++i) {
    int cc = ty + i * 8;
    out[(size_t)(c0 + cc) * R + r0 + tx] = f2bf(tile[tx][cc]);
  }
}

// ---------------------------------------------------------------------------
// 3) LayerNorm + FiLM modulate, fp32 -> bf16.  One row (1024) per block.
// ---------------------------------------------------------------------------
__global__ __launch_bounds__(256)
void ln_film(const float* __restrict__ x, const float* __restrict__ gamma,
             const float* __restrict__ cond, u16* __restrict__ xb) {
  int row = blockIdx.x;          // 0..4095
  int b = row >> 11;
  const float4 v = ((const float4*)(x + (size_t)row * DIM))[threadIdx.x];
  float s1 = v.x + v.y + v.z + v.w;
  float s2 = v.x * v.x + v.y * v.y + v.z * v.z + v.w * v.w;
#pragma unroll
  for (int m = 1; m <= 32; m <<= 1) {
    s1 += __shfl_xor(s1, m);
    s2 += __shfl_xor(s2, m);
  }
  __shared__ float red[8];
  int w = threadIdx.x >> 6, l = threadIdx.x & 63;
  if (l == 0) { red[w * 2] = s1; red[w * 2 + 1] = s2; }
  __syncthreads();
  s1 = red[0] + red[2] + red[4] + red[6];
  s2 = red[1] + red[3] + red[5] + red[7];
  float mu = s1 * (1.f / DIM);
  float var = s2 * (1.f / DIM) - mu * mu;
  float rstd = rsqrtf(var + 1e-5f);

  const float4 g  = ((const float4*)gamma)[threadIdx.x];
  const float4 sc = ((const float4*)(cond + b * 2048))[threadIdx.x];
  const float4 sh = ((const float4*)(cond + b * 2048 + 1024))[threadIdx.x];
  float y0 = (v.x - mu) * rstd * g.x * (sc.x + 1.f) + sh.x;
  float y1 = (v.y - mu) * rstd * g.y * (sc.y + 1.f) + sh.y;
  float y2 = (v.z - mu) * rstd * g.z * (sc.z + 1.f) + sh.z;
  float y3 = (v.w - mu) * rstd * g.w * (sc.w + 1.f) + sh.w;
  u32 p0 = (u32)f2bf(y0) | ((u32)f2bf(y1) << 16);
  u32 p1 = (u32)f2bf(y2) | ((u32)f2bf(y3) << 16);
  ((uint2*)(xb + (size_t)row * DIM))[threadIdx.x] = make_uint2(p0, p1);
}

// ---------------------------------------------------------------------------
// 4) bf16 MFMA GEMM, m97 structure: C[M,N] = A[M,K] * Bt[N,K]^T, K=1024
//    MODE 0: fused QK epilogue (gn<1024 -> Q *0.125*log2e, else K)
//    MODE 2: fp32 row-major output (stride 1024)
//    MODE 3: Vt  (A=WvT, Bt=xb): out[(b*1024+gm)*2048 + tok], coalesced
// ---------------------------------------------------------------------------
#define BM 128
#define BN 128
#define BK 32

#define SCALE_Q 0.18033688011112042f   // 0.125 * log2(e)

template <int MODE>
__global__ __launch_bounds__(256, 2)
void gemm_bt(const u16* __restrict__ A, const u16* __restrict__ Bt,
             void* __restrict__ out1, void* __restrict__ out2, int K) {
  __shared__ __align__(16) u16 aT[BM * BK];
  __shared__ __align__(16) u16 bT[BN * BK];
  const int t = threadIdx.x;
  const int w = t >> 6, l = t & 63, lr = l & 15, lg = l >> 4;
  const int wr = w >> 1, wc = w & 1;
  const int m0 = blockIdx.y * BM, n0 = blockIdx.x * BN;

  f32x4 acc[4][4] = {};

  const int nkt = K / BK;
  for (int kt = 0; kt < nkt; ++kt) {
    const u16* Asrc = A + (size_t)m0 * K + kt * BK;
    const u16* Bsrc = Bt + (size_t)n0 * K + kt * BK;
#pragma unroll
    for (int i = 0; i < 2; ++i) {
      int c = i * 256 + w * 64 + l;          // 16B chunk id, 0..511
      int row = c >> 2, cb = (c & 3) * 8;
      __builtin_amdgcn_global_load_lds(
          (const __attribute__((address_space(1))) void*)(Asrc + (size_t)row * K + cb),
          (__attribute__((address_space(3))) void*)(aT + (size_t)(i * 256 + w * 64) * 8),
          16, 0, 0);
    }
#pragma unroll
    for (int i = 0; i < 2; ++i) {
      int c = i * 256 + w * 64 + l;
      int row = c >> 2, cb = (c & 3) * 8;
      __builtin_amdgcn_global_load_lds(
          (const __attribute__((address_space(1))) void*)(Bsrc + (size_t)row * K + cb),
          (__attribute__((address_space(3))) void*)(bT + (size_t)(i * 256 + w * 64) * 8),
          16, 0, 0);
    }
    __syncthreads();

    bf16x8 af[4], bfr[4];
#pragma unroll
    for (int mt = 0; mt < 4; ++mt)
      af[mt] = *(const bf16x8*)(aT + (wr * 64 + mt * 16 + lr) * BK + lg * 8);
#pragma unroll
    for (int nt = 0; nt < 4; ++nt)
      bfr[nt] = *(const bf16x8*)(bT + (wc * 64 + nt * 16 + lr) * BK + lg * 8);
    __builtin_amdgcn_s_setprio(1);
#pragma unroll
    for (int mt = 0; mt < 4; ++mt)
#pragma unroll
      for (int nt = 0; nt < 4; ++nt)
        acc[mt][nt] = __builtin_amdgcn_mfma_f32_16x16x32_bf16(af[mt], bfr[nt],
                                                              acc[mt][nt], 0, 0, 0);
    __builtin_amdgcn_s_setprio(0);
    __syncthreads();
  }

  // epilogue: C/D layout col = lane&15, row = (lane>>4)*4 + reg
#pragma unroll
  for (int mt = 0; mt < 4; ++mt) {
#pragma unroll
    for (int nt = 0; nt < 4; ++nt) {
#pragma unroll
      for (int r = 0; r < 4; ++r) {
        int gm = m0 + wr * 64 + mt * 16 + lg * 4 + r;
        int gn = n0 + wc * 64 + nt * 16 + lr;
        float v = acc[mt][nt][r];
        if (MODE == 0) {
          int b = gm >> 11, tok = gm & 2047;
          if (gn < 1024) {        // Q (block-uniform branch)
            int h = gn >> 6, d = gn & 63;
            ((u16*)out1)[(((size_t)(b * HEADS + h) * NTOK + tok) << 6) + d] =
                f2bf(v * SCALE_Q);
          } else {                // K
            int c2 = gn - 1024;
            int h = c2 >> 6, d = c2 & 63;
            ((u16*)out2)[(((size_t)(b * HEADS + h) * NTOK + tok) << 6) + d] = f2bf(v);
          }
        } else if (MODE == 3) {   // Vt: gm = h*64+d (0..1023), gn = b*2048+tok
          ((u16*)out1)[(((size_t)(gn >> 11) * 1024 + gm) << 11) + (gn & 2047)] = f2bf(v);
        } else {
          ((float*)out1)[(size_t)gm * DIM + gn] = v;
        }
      }
    }
  }
}

// ---------------------------------------------------------------------------
// 5) Flash attention, swapped-operand / in-register-P version.
//    Grid (N/128, B*H), 8 waves/block (wave = 16 q-rows), KV tile = 64.
//    S^T = mfma(K,Q): lane owns q = lane&15; kv = nt*16 + (lane>>4)*4 + r.
//    P^T redistributed to PV B-frags via permlane32/16 swaps (3-cycle of
//    bit permutation: reg-bit0 -> lane-bit5 -> lane-bit4 -> reg-bit0).
// ---------------------------------------------------------------------------
__global__ __launch_bounds__(512, 4)
void attn_kernel(const u16* __restrict__ Q, const u16* __restrict__ K,
                 const u16* __restrict__ Vt, u16* __restrict__ Aout) {
  __shared__ __align__(16) u16 kbuf[2][64 * 64];
  __shared__ __align__(16) u16 vbuf[2][64 * 64];
  int bh = blockIdx.y;
  int b = bh >> 4, h = bh & 15;
  int w = threadIdx.x >> 6, l = threadIdx.x & 63, lr = l & 15, lg = l >> 4;
  int q0 = blockIdx.x * 128 + w * 16;
  const u16* Qh = Q + ((size_t)bh << 17);   // 2048*64
  const u16* Kh = K + ((size_t)bh << 17);
  const u16* Vh = Vt + ((size_t)bh << 17);

  // Q as PV-style fragment (B-operand): n=q=lr, k = kt*32 + lg*8 + j
  bf16x8 qf[2];
  qf[0] = *(const bf16x8*)(Qh + (size_t)(q0 + lr) * 64 + lg * 8);
  qf[1] = *(const bf16x8*)(Qh + (size_t)(q0 + lr) * 64 + 32 + lg * 8);

  f32x4 o[4] = {};                 // O^T: d = nt*16 + lg*4 + r, q = lr
  float mm = -3.0e38f, ls = 0.f;   // per-lane scalars (q = lr)

  auto stage = [&](int buf, int kv0) {
    int c = threadIdx.x;                         // chunk 0..511
    int row = c >> 3;
    int sl = (c & 7) ^ (row & 7);                // pre-swizzled source slot
    int wb = (c >> 6) << 9;                      // w*512 u16 dest base
    __builtin_amdgcn_global_load_lds(
        (const __attribute__((address_space(1))) void*)(Kh + (size_t)(kv0 + row) * 64 + sl * 8),
        (__attribute__((address_space(3))) void*)(&kbuf[buf][wb]), 16, 0, 0);
    __builtin_amdgcn_global_load_lds(
        (const __attribute__((address_space(1))) void*)(Vh + (size_t)row * NTOK + kv0 + sl * 8),
        (__attribute__((address_space(3))) void*)(&vbuf[buf][wb]), 16, 0, 0);
  };

  stage(0, 0);
  __syncthreads();

  for (int t = 0; t < NTOK / 64; ++t) {
    int cur = t & 1;
    if (t < NTOK / 64 - 1) stage(cur ^ 1, (t + 1) * 64);

    const u16* kb = kbuf[cur];
    const u16* vb = vbuf[cur];

    // S^T[kv][q] = K·Q : lane holds q=lr, kv = nt*16 + lg*4 + r
    f32x4 s[4] = {};
#pragma unroll
    for (int kt = 0; kt < 2; ++kt) {
      bf16x8 kf[4];
#pragma unroll
      for (int nt = 0; nt < 4; ++nt) {
        int row = nt * 16 + lr;
        int slot = (kt * 4 + lg) ^ (row & 7);
        kf[nt] = *(const bf16x8*)(kb + row * 64 + slot * 8);
      }
      __builtin_amdgcn_s_setprio(1);
#pragma unroll
      for (int nt = 0; nt < 4; ++nt)
        s[nt] = __builtin_amdgcn_mfma_f32_16x16x32_bf16(kf[nt], qf[kt], s[nt], 0, 0, 0);
      __builtin_amdgcn_s_setprio(0);
    }

    // --- lane-local online softmax (scores already in log2 domain) ---
    float tm = s[0][0];
#pragma unroll
    for (int nt = 0; nt < 4; ++nt)
#pragma unroll
      for (int r = 0; r < 4; ++r) tm = fmaxf(tm, s[nt][r]);
    tm = fmaxf(tm, __shfl_xor(tm, 16));
    tm = fmaxf(tm, __shfl_xor(tm, 32));
    float mn = fmaxf(mm, tm);
    float al = __builtin_amdgcn_exp2f(mm - mn);
    mm = mn;

    float rs = 0.f;
    u32 W[2][2][2];                 // [nt1][nt0][w]
#pragma unroll
    for (int n1 = 0; n1 < 2; ++n1) {
#pragma unroll
      for (int n0 = 0; n0 < 2; ++n0) {
        int nt = n1 * 2 + n0;
        float p0 = __builtin_amdgcn_exp2f(s[nt][0] - mn);
        float p1 = __builtin_amdgcn_exp2f(s[nt][1] - mn);
        float p2 = __builtin_amdgcn_exp2f(s[nt][2] - mn);
        float p3 = __builtin_amdgcn_exp2f(s[nt][3] - mn);
        rs += (p0 + p1) + (p2 + p3);
        asm("v_cvt_pk_bf16_f32 %0, %1, %2" : "=v"(W[n1][n0][0]) : "v"(p0), "v"(p1));
        asm("v_cvt_pk_bf16_f32 %0, %1, %2" : "=v"(W[n1][n0][1]) : "v"(p2), "v"(p3));
      }
    }
    rs += __shfl_xor(rs, 16);
    rs += __shfl_xor(rs, 32);
    ls = ls * al + rs;

    // S1: exchange reg-bit0 (nt0) <-> lane-bit5
#pragma unroll
    for (int n1 = 0; n1 < 2; ++n1)
#pragma unroll
      for (int wd = 0; wd < 2; ++wd)
        asm volatile("v_permlane32_swap_b32 %0, %1"
                     : "+v"(W[n1][0][wd]), "+v"(W[n1][1][wd]));
    // S2: exchange reg-bit0 <-> lane-bit4
#pragma unroll
    for (int n1 = 0; n1 < 2; ++n1)
#pragma unroll
      for (int wd = 0; wd < 2; ++wd)
        asm volatile("v_permlane16_swap_b32 %0, %1"
                     : "+v"(W[n1][0][wd]), "+v"(W[n1][1][wd]));

    // rescale O^T
#pragma unroll
    for (int nt = 0; nt < 4; ++nt)
#pragma unroll
      for (int r = 0; r < 4; ++r) o[nt][r] *= al;

    // PV: O^T[d][q] += Vt[d][kv] · P^T[kv][q]
#pragma unroll
    for (int kt = 0; kt < 2; ++kt) {
      u32x4 pw = {W[kt][0][0], W[kt][0][1], W[kt][1][0], W[kt][1][1]};
      bf16x8 pb = __builtin_bit_cast(bf16x8, pw);
      bf16x8 vf[4];
#pragma unroll
      for (int nt = 0; nt < 4; ++nt) {
        int row = nt * 16 + lr;
        int slot = (kt * 4 + lg) ^ (row & 7);
        vf[nt] = *(const bf16x8*)(vb + row * 64 + slot * 8);
      }
      __builtin_amdgcn_s_setprio(1);
#pragma unroll
      for (int nt = 0; nt < 4; ++nt)
        o[nt] = __builtin_amdgcn_mfma_f32_16x16x32_bf16(vf[nt], pb, o[nt], 0, 0, 0);
      __builtin_amdgcn_s_setprio(0);
    }
    __syncthreads();   // drains prefetch (vmcnt) + flips buffer
  }

  // write: lane holds O^T column q=lr, rows d = nt*16 + lg*4 + r
  float inv = 1.f / ls;
  int tok = q0 + lr;
  u16* orow = Aout + ((size_t)(b * NTOK + tok)) * DIM + h * DHEAD;
#pragma unroll
  for (int nt = 0; nt < 4; ++nt) {
    u32 w0 = (u32)f2bf(o[nt][0] * inv) | ((u32)f2bf(o[nt][1] * inv) << 16);
    u32 w1 = (u32)f2bf(o[nt][2] * inv) | ((u32)f2bf(o[nt][3] * inv) << 16);
    *(uint2*)(orow + nt * 16 + lg * 4) = make_uint2(w0, w1);
  }
}

// ---------------------------------------------------------------------------
// launch
// ---------------------------------------------------------------------------
extern "C" void kernel_launch(void* const* d_in, const int* in_sizes, int n_in,
                              void* d_out, int out_size, void* d_ws, size_t ws_size,
                              hipStream_t stream) {
  const float* x     = (const float*)d_in[0];
  const float* ce    = (const float*)d_in[1];
  const float* gamma = (const float*)d_in[2];
  const float* cW    = (const float*)d_in[3];
  const float* cb    = (const float*)d_in[4];
  const float* Wq    = (const float*)d_in[5];
  const float* Wkv   = (const float*)d_in[6];
  const float* Wo    = (const float*)d_in[7];
  float* out = (float*)d_out;

  char* ws = (char*)d_ws;
  float* cond = (float*)ws;                               // 16 KB
  u16* WT   = (u16*)(ws + (16 << 10));                    // [3072][1024] bf16 = 6 MB
  u16* WoT  = (u16*)(ws + (16 << 10) + (6u << 20));       // 2 MB
  u16* xb   = (u16*)(ws + (16 << 10) + (8u << 20));       // 8 MB
  u16* Qb   = (u16*)(ws + (16 << 10) + (16u << 20));      // 8 MB
  u16* Kb   = (u16*)(ws + (16 << 10) + (24u << 20));      // 8 MB
  u16* Vtb  = (u16*)(ws + (16 << 10) + (32u << 20));      // 8 MB
  u16* Ab   = (u16*)(ws + (16 << 10) + (40u << 20));      // 8 MB
  u16* WvT  = WT + 2048 * 1024;

  hipMemsetAsync(cond, 0, 16 << 10, stream);
  cond_mlp<<<128, 256, 0, stream>>>(ce, cW, cb, cond);
  transpose_cast<<<dim3(32, 32), 256, 0, stream>>>(Wq, WT, 1024, 1024);
  transpose_cast<<<dim3(64, 32), 256, 0, stream>>>(Wkv, WT + 1024 * 1024, 1024, 2048);
  transpose_cast<<<dim3(32, 32), 256, 0, stream>>>(Wo, WoT, 1024, 1024);
  ln_film<<<4096, 256, 0, stream>>>(x, gamma, cond, xb);
  gemm_bt<0><<<dim3(16, 32), 256, 0, stream>>>(xb, WT, Qb, Kb, 1024);       // fused Q+K
  gemm_bt<3><<<dim3(32, 8), 256, 0, stream>>>(WvT, xb, Vtb, nullptr, 1024); // Vt = (x@Wv)^T
  attn_kernel<<<dim3(16, 32), 512, 0, stream>>>(Qb, Kb, Vtb, Ab);
  gemm_bt<2><<<dim3(8, 32), 256, 0, stream>>>(Ab, WoT, out, nullptr, 1024);
}

// Round 4
// 238.300 us; speedup vs baseline: 2.3257x; 1.0415x over previous
//
#include <hip/hip_runtime.h>

// ---------------------------------------------------------------------------
// Round 3: GEMMs get prefetch-overlap double-buffering (T3-minimum) +
// both-sides XOR swizzle; attn gets XCD-aware block mapping + defer-max;
// transposes fused into one dispatch.
// ---------------------------------------------------------------------------

typedef __bf16 bf16x8 __attribute__((ext_vector_type(8)));
typedef float  f32x4  __attribute__((ext_vector_type(4)));
typedef unsigned int u32x4 __attribute__((ext_vector_type(4)));
using u16 = unsigned short;
using u32 = unsigned int;

#define DIM   1024
#define NTOK  2048
#define HEADS 16
#define DHEAD 64

__device__ __forceinline__ u16 f2bf(float f) {
  u32 u = __builtin_bit_cast(u32, f);
  u += 0x7fffu + ((u >> 16) & 1u);   // RNE
  return (u16)(u >> 16);
}

// ---------------------------------------------------------------------------
// 1) FiLM conditioning MLP, split-K with atomics. grid 128 = b(2) x kb(8) x jb(8)
// ---------------------------------------------------------------------------
__global__ void cond_mlp(const float* __restrict__ ce, const float* __restrict__ W,
                         const float* __restrict__ bias, float* __restrict__ cond) {
  int b  = blockIdx.x >> 6;
  int kb = (blockIdx.x >> 3) & 7;
  int j  = (blockIdx.x & 7) * 256 + threadIdx.x;     // 0..2047
  const float* cb = ce + b * 1024;
  float acc = (kb == 0) ? bias[j] : 0.f;
  int k0 = kb * 128;
  for (int k = k0; k < k0 + 128; ++k) {
    float t = cb[k];
    float s = t / (1.f + __expf(-t));                // silu
    acc += s * W[k * 2048 + j];
  }
  atomicAdd(&cond[b * 2048 + j], acc);
}

// ---------------------------------------------------------------------------
// 2) fused transpose + cast for all 3 weights: fp32 [R][C] -> bf16 [C][R]
//    grid 4096: [0,1024) Wq, [1024,3072) Wkv, [3072,4096) Wo
// ---------------------------------------------------------------------------
__global__ void transpose_cast_all(const float* __restrict__ Wq,
                                   const float* __restrict__ Wkv,
                                   const float* __restrict__ Wo,
                                   u16* __restrict__ WT, u16* __restrict__ WoT) {
  int id = blockIdx.x;
  const float* in; u16* out; int R = 1024, C;
  if (id < 1024)       { in = Wq;  out = WT;               C = 1024; }
  else if (id < 3072)  { in = Wkv; out = WT + 1024 * 1024; C = 2048; id -= 1024; }
  else                 { in = Wo;  out = WoT;              C = 1024; id -= 3072; }
  int nbx = C >> 5;
  int c0 = (id % nbx) * 32, r0 = (id / nbx) * 32;

  __shared__ float tile[32][33];
  int tx = threadIdx.x & 31, ty = threadIdx.x >> 5;       // 32 x 8
#pragma unroll
  for (int i = 0; i < 4; ++i) {
    int r = ty + i * 8;
    tile[r][tx] = in[(size_t)(r0 + r) * C + c0 + tx];
  }
  __syncthreads();
#pragma unroll
  for (int i = 0; i < 4; ++i) {
    int cc = ty + i * 8;
    out[(size_t)(c0 + cc) * R + r0 + tx] = f2bf(tile[tx][cc]);
  }
}

// ---------------------------------------------------------------------------
// 3) LayerNorm + FiLM modulate, fp32 -> bf16.  One row (1024) per block.
// ---------------------------------------------------------------------------
__global__ __launch_bounds__(256)
void ln_film(const float* __restrict__ x, const float* __restrict__ gamma,
             const float* __restrict__ cond, u16* __restrict__ xb) {
  int row = blockIdx.x;          // 0..4095
  int b = row >> 11;
  const float4 v = ((const float4*)(x + (size_t)row * DIM))[threadIdx.x];
  float s1 = v.x + v.y + v.z + v.w;
  float s2 = v.x * v.x + v.y * v.y + v.z * v.z + v.w * v.w;
#pragma unroll
  for (int m = 1; m <= 32; m <<= 1) {
    s1 += __shfl_xor(s1, m);
    s2 += __shfl_xor(s2, m);
  }
  __shared__ float red[8];
  int w = threadIdx.x >> 6, l = threadIdx.x & 63;
  if (l == 0) { red[w * 2] = s1; red[w * 2 + 1] = s2; }
  __syncthreads();
  s1 = red[0] + red[2] + red[4] + red[6];
  s2 = red[1] + red[3] + red[5] + red[7];
  float mu = s1 * (1.f / DIM);
  float var = s2 * (1.f / DIM) - mu * mu;
  float rstd = rsqrtf(var + 1e-5f);

  const float4 g  = ((const float4*)gamma)[threadIdx.x];
  const float4 sc = ((const float4*)(cond + b * 2048))[threadIdx.x];
  const float4 sh = ((const float4*)(cond + b * 2048 + 1024))[threadIdx.x];
  float y0 = (v.x - mu) * rstd * g.x * (sc.x + 1.f) + sh.x;
  float y1 = (v.y - mu) * rstd * g.y * (sc.y + 1.f) + sh.y;
  float y2 = (v.z - mu) * rstd * g.z * (sc.z + 1.f) + sh.z;
  float y3 = (v.w - mu) * rstd * g.w * (sc.w + 1.f) + sh.w;
  u32 p0 = (u32)f2bf(y0) | ((u32)f2bf(y1) << 16);
  u32 p1 = (u32)f2bf(y2) | ((u32)f2bf(y3) << 16);
  ((uint2*)(xb + (size_t)row * DIM))[threadIdx.x] = make_uint2(p0, p1);
}

// ---------------------------------------------------------------------------
// 4) bf16 MFMA GEMM, double-buffered: stage(next) || compute(cur), 1 barrier/tile.
//    Both-sides XOR swizzle (slot ^= row&3) kills the 8-way ds_read conflict.
//    MODE 0: fused QK epilogue (gn<1024 -> Q *0.125*log2e, else K)
//    MODE 2: fp32 row-major output (stride 1024)
//    MODE 3: Vt  (A=WvT, Bt=xb): out[(b*1024+gm)*2048 + tok], coalesced
// ---------------------------------------------------------------------------
#define BM 128
#define BN 128
#define BK 32

#define SCALE_Q 0.18033688011112042f   // 0.125 * log2(e)

template <int MODE>
__global__ __launch_bounds__(256, 2)
void gemm_bt(const u16* __restrict__ A, const u16* __restrict__ Bt,
             void* __restrict__ out1, void* __restrict__ out2, int K) {
  __shared__ __align__(16) u16 aT[2][BM * BK];
  __shared__ __align__(16) u16 bT[2][BN * BK];
  const int t = threadIdx.x;
  const int w = t >> 6, l = t & 63, lr = l & 15, lg = l >> 4;
  const int wr = w >> 1, wc = w & 1;
  const int m0 = blockIdx.y * BM, n0 = blockIdx.x * BN;

  f32x4 acc[4][4] = {};
  const int nkt = K / BK;

  auto stage = [&](int buf, int kt) {
    const u16* Asrc = A + (size_t)m0 * K + kt * BK;
    const u16* Bsrc = Bt + (size_t)n0 * K + kt * BK;
#pragma unroll
    for (int i = 0; i < 2; ++i) {
      int c = i * 256 + w * 64 + l;          // 16B chunk id, 0..511
      int row = c >> 2, sl = (c & 3) ^ (row & 3);   // pre-swizzled source slot
      __builtin_amdgcn_global_load_lds(
          (const __attribute__((address_space(1))) void*)(Asrc + (size_t)row * K + sl * 8),
          (__attribute__((address_space(3))) void*)(&aT[buf][(i * 256 + w * 64) * 8]),
          16, 0, 0);
    }
#pragma unroll
    for (int i = 0; i < 2; ++i) {
      int c = i * 256 + w * 64 + l;
      int row = c >> 2, sl = (c & 3) ^ (row & 3);
      __builtin_amdgcn_global_load_lds(
          (const __attribute__((address_space(1))) void*)(Bsrc + (size_t)row * K + sl * 8),
          (__attribute__((address_space(3))) void*)(&bT[buf][(i * 256 + w * 64) * 8]),
          16, 0, 0);
    }
  };

  stage(0, 0);
  __syncthreads();

  for (int kt = 0; kt < nkt; ++kt) {
    int cur = kt & 1;
    if (kt + 1 < nkt) stage(cur ^ 1, kt + 1);   // overlaps with compute below

    bf16x8 af[4], bfr[4];
#pragma unroll
    for (int mt = 0; mt < 4; ++mt) {
      int row = wr * 64 + mt * 16 + lr;
      af[mt] = *(const bf16x8*)(&aT[cur][row * BK + (lg ^ (row & 3)) * 8]);
    }
#pragma unroll
    for (int nt = 0; nt < 4; ++nt) {
      int row = wc * 64 + nt * 16 + lr;
      bfr[nt] = *(const bf16x8*)(&bT[cur][row * BK + (lg ^ (row & 3)) * 8]);
    }
    __builtin_amdgcn_s_setprio(1);
#pragma unroll
    for (int mt = 0; mt < 4; ++mt)
#pragma unroll
      for (int nt = 0; nt < 4; ++nt)
        acc[mt][nt] = __builtin_amdgcn_mfma_f32_16x16x32_bf16(af[mt], bfr[nt],
                                                              acc[mt][nt], 0, 0, 0);
    __builtin_amdgcn_s_setprio(0);
    __syncthreads();   // drains prefetch, flips buffer
  }

  // epilogue: C/D layout col = lane&15, row = (lane>>4)*4 + reg
#pragma unroll
  for (int mt = 0; mt < 4; ++mt) {
#pragma unroll
    for (int nt = 0; nt < 4; ++nt) {
#pragma unroll
      for (int r = 0; r < 4; ++r) {
        int gm = m0 + wr * 64 + mt * 16 + lg * 4 + r;
        int gn = n0 + wc * 64 + nt * 16 + lr;
        float v = acc[mt][nt][r];
        if (MODE == 0) {
          int b = gm >> 11, tok = gm & 2047;
          if (gn < 1024) {        // Q (block-uniform branch)
            int h = gn >> 6, d = gn & 63;
            ((u16*)out1)[(((size_t)(b * HEADS + h) * NTOK + tok) << 6) + d] =
                f2bf(v * SCALE_Q);
          } else {                // K
            int c2 = gn - 1024;
            int h = c2 >> 6, d = c2 & 63;
            ((u16*)out2)[(((size_t)(b * HEADS + h) * NTOK + tok) << 6) + d] = f2bf(v);
          }
        } else if (MODE == 3) {   // Vt: gm = h*64+d (0..1023), gn = b*2048+tok
          ((u16*)out1)[(((size_t)(gn >> 11) * 1024 + gm) << 11) + (gn & 2047)] = f2bf(v);
        } else {
          ((float*)out1)[(size_t)gm * DIM + gn] = v;
        }
      }
    }
  }
}

// ---------------------------------------------------------------------------
// 5) Flash attention, swapped-operand / in-register-P, defer-max, XCD-aware.
//    1-D grid 512: bh = id&31 (XCD = id%8 fixed per bh -> K/V L2-resident),
//    qchunk = id>>5. 8 waves/block, wave = 16 q-rows, KV tile = 64.
// ---------------------------------------------------------------------------
__global__ __launch_bounds__(512, 4)
void attn_kernel(const u16* __restrict__ Q, const u16* __restrict__ K,
                 const u16* __restrict__ Vt, u16* __restrict__ Aout) {
  __shared__ __align__(16) u16 kbuf[2][64 * 64];
  __shared__ __align__(16) u16 vbuf[2][64 * 64];
  int bid = blockIdx.x;
  int bh = bid & 31, qc = bid >> 5;
  int b = bh >> 4, h = bh & 15;
  int w = threadIdx.x >> 6, l = threadIdx.x & 63, lr = l & 15, lg = l >> 4;
  int q0 = qc * 128 + w * 16;
  const u16* Qh = Q + ((size_t)bh << 17);   // 2048*64
  const u16* Kh = K + ((size_t)bh << 17);
  const u16* Vh = Vt + ((size_t)bh << 17);

  // Q as B-operand fragment: n=q=lr, k = kt*32 + lg*8 + j
  bf16x8 qf[2];
  qf[0] = *(const bf16x8*)(Qh + (size_t)(q0 + lr) * 64 + lg * 8);
  qf[1] = *(const bf16x8*)(Qh + (size_t)(q0 + lr) * 64 + 32 + lg * 8);

  f32x4 o[4] = {};                 // O^T: d = nt*16 + lg*4 + r, q = lr
  float mm = -3.0e38f, ls = 0.f;   // per-lane scalars (q = lr)

  auto stage = [&](int buf, int kv0) {
    int c = threadIdx.x;                         // chunk 0..511
    int row = c >> 3;
    int sl = (c & 7) ^ (row & 7);                // pre-swizzled source slot
    int wb = (c >> 6) << 9;                      // w*512 u16 dest base
    __builtin_amdgcn_global_load_lds(
        (const __attribute__((address_space(1))) void*)(Kh + (size_t)(kv0 + row) * 64 + sl * 8),
        (__attribute__((address_space(3))) void*)(&kbuf[buf][wb]), 16, 0, 0);
    __builtin_amdgcn_global_load_lds(
        (const __attribute__((address_space(1))) void*)(Vh + (size_t)row * NTOK + kv0 + sl * 8),
        (__attribute__((address_space(3))) void*)(&vbuf[buf][wb]), 16, 0, 0);
  };

  stage(0, 0);
  __syncthreads();

  for (int t = 0; t < NTOK / 64; ++t) {
    int cur = t & 1;
    if (t < NTOK / 64 - 1) stage(cur ^ 1, (t + 1) * 64);

    const u16* kb = kbuf[cur];
    const u16* vb = vbuf[cur];

    // S^T[kv][q] = K·Q : lane holds q=lr, kv = nt*16 + lg*4 + r
    f32x4 s[4] = {};
#pragma unroll
    for (int kt = 0; kt < 2; ++kt) {
      bf16x8 kf[4];
#pragma unroll
      for (int nt = 0; nt < 4; ++nt) {
        int row = nt * 16 + lr;
        int slot = (kt * 4 + lg) ^ (row & 7);
        kf[nt] = *(const bf16x8*)(kb + row * 64 + slot * 8);
      }
      __builtin_amdgcn_s_setprio(1);
#pragma unroll
      for (int nt = 0; nt < 4; ++nt)
        s[nt] = __builtin_amdgcn_mfma_f32_16x16x32_bf16(kf[nt], qf[kt], s[nt], 0, 0, 0);
      __builtin_amdgcn_s_setprio(0);
    }

    // --- lane-local online softmax with defer-max (log2 domain) ---
    float a0 = fmaxf(fmaxf(s[0][0], s[0][1]), fmaxf(s[0][2], s[0][3]));
    float a1 = fmaxf(fmaxf(s[1][0], s[1][1]), fmaxf(s[1][2], s[1][3]));
    float a2 = fmaxf(fmaxf(s[2][0], s[2][1]), fmaxf(s[2][2], s[2][3]));
    float a3 = fmaxf(fmaxf(s[3][0], s[3][1]), fmaxf(s[3][2], s[3][3]));
    float tm = fmaxf(fmaxf(a0, a1), fmaxf(a2, a3));
    tm = fmaxf(tm, __shfl_xor(tm, 16));
    tm = fmaxf(tm, __shfl_xor(tm, 32));
    if (__any((int)(tm > mm + 8.f))) {        // wave-uniform rescale path
      float mn = fmaxf(mm, tm);
      float al = __builtin_amdgcn_exp2f(mm - mn);
      mm = mn;
#pragma unroll
      for (int nt = 0; nt < 4; ++nt)
#pragma unroll
        for (int r = 0; r < 4; ++r) o[nt][r] *= al;
      ls *= al;
    }

    float rs = 0.f;
    u32 W[2][2][2];                 // [kt][nt0][w]
#pragma unroll
    for (int n1 = 0; n1 < 2; ++n1) {
#pragma unroll
      for (int n0 = 0; n0 < 2; ++n0) {
        int nt = n1 * 2 + n0;
        float p0 = __builtin_amdgcn_exp2f(s[nt][0] - mm);
        float p1 = __builtin_amdgcn_exp2f(s[nt][1] - mm);
        float p2 = __builtin_amdgcn_exp2f(s[nt][2] - mm);
        float p3 = __builtin_amdgcn_exp2f(s[nt][3] - mm);
        rs += (p0 + p1) + (p2 + p3);
        asm("v_cvt_pk_bf16_f32 %0, %1, %2" : "=v"(W[n1][n0][0]) : "v"(p0), "v"(p1));
        asm("v_cvt_pk_bf16_f32 %0, %1, %2" : "=v"(W[n1][n0][1]) : "v"(p2), "v"(p3));
      }
    }
    rs += __shfl_xor(rs, 16);
    rs += __shfl_xor(rs, 32);
    ls += rs;

    // P^T redistribution: reg-bit0 <-> lane-bit5, then reg-bit0 <-> lane-bit4
#pragma unroll
    for (int n1 = 0; n1 < 2; ++n1)
#pragma unroll
      for (int wd = 0; wd < 2; ++wd)
        asm volatile("v_permlane32_swap_b32 %0, %1"
                     : "+v"(W[n1][0][wd]), "+v"(W[n1][1][wd]));
#pragma unroll
    for (int n1 = 0; n1 < 2; ++n1)
#pragma unroll
      for (int wd = 0; wd < 2; ++wd)
        asm volatile("v_permlane16_swap_b32 %0, %1"
                     : "+v"(W[n1][0][wd]), "+v"(W[n1][1][wd]));

    // PV: O^T[d][q] += Vt[d][kv] · P^T[kv][q]
#pragma unroll
    for (int kt = 0; kt < 2; ++kt) {
      u32x4 pw = {W[kt][0][0], W[kt][0][1], W[kt][1][0], W[kt][1][1]};
      bf16x8 pb = __builtin_bit_cast(bf16x8, pw);
      bf16x8 vf[4];
#pragma unroll
      for (int nt = 0; nt < 4; ++nt) {
        int row = nt * 16 + lr;
        int slot = (kt * 4 + lg) ^ (row & 7);
        vf[nt] = *(const bf16x8*)(vb + row * 64 + slot * 8);
      }
      __builtin_amdgcn_s_setprio(1);
#pragma unroll
      for (int nt = 0; nt < 4; ++nt)
        o[nt] = __builtin_amdgcn_mfma_f32_16x16x32_bf16(vf[nt], pb, o[nt], 0, 0, 0);
      __builtin_amdgcn_s_setprio(0);
    }
    __syncthreads();   // drains prefetch (vmcnt) + flips buffer
  }

  // write: lane holds O^T column q=lr, rows d = nt*16 + lg*4 + r
  float inv = 1.f / ls;
  int tok = q0 + lr;
  u16* orow = Aout + ((size_t)(b * NTOK + tok)) * DIM + h * DHEAD;
#pragma unroll
  for (int nt = 0; nt < 4; ++nt) {
    u32 w0 = (u32)f2bf(o[nt][0] * inv) | ((u32)f2bf(o[nt][1] * inv) << 16);
    u32 w1 = (u32)f2bf(o[nt][2] * inv) | ((u32)f2bf(o[nt][3] * inv) << 16);
    *(uint2*)(orow + nt * 16 + lg * 4) = make_uint2(w0, w1);
  }
}

// ---------------------------------------------------------------------------
// launch
// ---------------------------------------------------------------------------
extern "C" void kernel_launch(void* const* d_in, const int* in_sizes, int n_in,
                              void* d_out, int out_size, void* d_ws, size_t ws_size,
                              hipStream_t stream) {
  const float* x     = (const float*)d_in[0];
  const float* ce    = (const float*)d_in[1];
  const float* gamma = (const float*)d_in[2];
  const float* cW    = (const float*)d_in[3];
  const float* cb    = (const float*)d_in[4];
  const float* Wq    = (const float*)d_in[5];
  const float* Wkv   = (const float*)d_in[6];
  const float* Wo    = (const float*)d_in[7];
  float* out = (float*)d_out;

  char* ws = (char*)d_ws;
  float* cond = (float*)ws;                               // 16 KB
  u16* WT   = (u16*)(ws + (16 << 10));                    // [3072][1024] bf16 = 6 MB
  u16* WoT  = (u16*)(ws + (16 << 10) + (6u << 20));       // 2 MB
  u16* xb   = (u16*)(ws + (16 << 10) + (8u << 20));       // 8 MB
  u16* Qb   = (u16*)(ws + (16 << 10) + (16u << 20));      // 8 MB
  u16* Kb   = (u16*)(ws + (16 << 10) + (24u << 20));      // 8 MB
  u16* Vtb  = (u16*)(ws + (16 << 10) + (32u << 20));      // 8 MB
  u16* Ab   = (u16*)(ws + (16 << 10) + (40u << 20));      // 8 MB
  u16* WvT  = WT + 2048 * 1024;

  hipMemsetAsync(cond, 0, 16 << 10, stream);
  cond_mlp<<<128, 256, 0, stream>>>(ce, cW, cb, cond);
  transpose_cast_all<<<4096, 256, 0, stream>>>(Wq, Wkv, Wo, WT, WoT);
  ln_film<<<4096, 256, 0, stream>>>(x, gamma, cond, xb);
  gemm_bt<0><<<dim3(16, 32), 256, 0, stream>>>(xb, WT, Qb, Kb, 1024);       // fused Q+K
  gemm_bt<3><<<dim3(32, 8), 256, 0, stream>>>(WvT, xb, Vtb, nullptr, 1024); // Vt = (x@Wv)^T
  attn_kernel<<<512, 512, 0, stream>>>(Qb, Kb, Vtb, Ab);
  gemm_bt<2><<<dim3(8, 32), 256, 0, stream>>>(Ab, WoT, out, nullptr, 1024);
}